// Round 8
// baseline (456.676 us; speedup 1.0000x reference)
//
#include <hip/hip_runtime.h>

typedef unsigned int u32;
typedef __fp16 half2_t __attribute__((ext_vector_type(2)));
typedef __fp16 half8_t __attribute__((ext_vector_type(8)));
typedef float  f32x4   __attribute__((ext_vector_type(4)));

#define DIN 128
#define DH  128
#define SEQL 512
#define NBATCH 256
#define NC  512          // 4*DH fused gate columns
#define TC  64           // timesteps per chunk
#define NCHUNK (SEQL/TC) // 8

#define HOFF  65536              // hbuf f16[128] (256 B), single buffer
#define GOFF  (65536 + 256)      // gates f32[128 j][4 g] (2 KB)
#define LDS_TOTAL (65536 + 256 + 2048)

__device__ __forceinline__ u32 pk2(float a, float b) {
  half2_t h = __builtin_amdgcn_cvt_pkrtz(a, b);
  return __builtin_bit_cast(u32, h);
}

__device__ __forceinline__ float fexp2(float x) {
#if defined(__has_builtin) && __has_builtin(__builtin_amdgcn_exp2f)
  return __builtin_amdgcn_exp2f(x);
#else
  return __builtin_exp2f(x);
#endif
}

__device__ __forceinline__ float dot2(u32 a, u32 b, float c) {
#if defined(__has_builtin) && __has_builtin(__builtin_amdgcn_fdot2)
  return __builtin_amdgcn_fdot2(__builtin_bit_cast(half2_t, a),
                                __builtin_bit_cast(half2_t, b), c, false);
#else
  half2_t ha = __builtin_bit_cast(half2_t, a);
  half2_t hb = __builtin_bit_cast(half2_t, b);
  return c + (float)ha[0]*(float)hb[0] + (float)ha[1]*(float)hb[1];
#endif
}

#define MF(A, B, C) __builtin_amdgcn_mfma_f32_16x16x32_f16( \
    __builtin_bit_cast(half8_t, A), __builtin_bit_cast(half8_t, B), C, 0, 0, 0)

// Pack fused weight matrices into f16-pair (k-pair) column-major images:
// wT[j][kk] = (w[2kk][j], w[2kk+1][j]),  j in [0,512), kk in [0,64)
__global__ void pack_w(const float* __restrict__ x2i, const float* __restrict__ x2f,
                       const float* __restrict__ x2g, const float* __restrict__ x2o,
                       const float* __restrict__ h2i, const float* __restrict__ h2f,
                       const float* __restrict__ h2g, const float* __restrict__ h2o,
                       u32* __restrict__ wxT, u32* __restrict__ whT) {
  int idx = blockIdx.x * blockDim.x + threadIdx.x;   // 0..32767
  if (idx >= NC * 64) return;
  int j = idx >> 6, kk = idx & 63;
  int g = j >> 7, jjj = j & 127;
  const float* wx = (g == 0) ? x2i : (g == 1) ? x2f : (g == 2) ? x2g : x2o;
  const float* wh = (g == 0) ? h2i : (g == 1) ? h2f : (g == 2) ? h2g : h2o;
  wxT[idx] = pk2(wx[(2*kk)*DH + jjj], wx[(2*kk+1)*DH + jjj]);
  whT[idx] = pk2(wh[(2*kk)*DH + jjj], wh[(2*kk+1)*DH + jjj]);
}

// LDS: xgT [512 col][128 B of t, XOR-swizzled f16] = 64 KB ; hbuf ; gates
__global__ __launch_bounds__(512, 2)
void lstm_fused(
    const float* __restrict__ x, const u32* __restrict__ wxT,
    const u32* __restrict__ whT, const float* __restrict__ w_out,
    float* __restrict__ out) {
  extern __shared__ char lds[];
  char* xgT = lds;

  const int tid = threadIdx.x;
  const int b   = blockIdx.x;
  const int l   = tid & 63, wv = tid >> 6;
  const int kg  = l >> 4, r15 = l & 15;
  const bool mfmaRole = (wv < 4);       // waves round-robin SIMDs: each SIMD
                                        // gets one MFMA-wave + one VALU-wave
  // updater (MFMA-waves only, dup x2): hidden index ju
  const int ju  = (wv & 3) * 32 + (l & 31);
  // VALU-wave coords
  const int vix = wv - 4;               // 0..3 (valid when !mfmaRole)
  const int gslot = 2 + ((vix >> 1) & 1);  // 2 = gate g, 3 = gate o
  const int jv  = (vix & 1) * 64 + l;      // hidden col owned by lane

  // ---- persistent recurrence weights (one 16xuint4 array, role-divergent) ----
  // MFMA role: B-frags for tiles {i@j0, i@j1, f@j0, f@j1}, j0=16wv+r15, j1=64+16wv+r15
  //   wreg[t*4+kt] = whT[(gbase + cblk + r15)*64][kt*4+kg]
  // VALU role: full col gslot*128+jv: wreg[mm] = whT[col*64][mm]
  uint4 wreg[16];
  if (mfmaRole) {
#pragma unroll
    for (int t = 0; t < 4; ++t) {
      int col = (t >> 1) * DH + (t & 1) * 64 + wv * 16 + r15;
      const uint4* wp = (const uint4*)(whT + col * 64);
#pragma unroll
      for (int kt = 0; kt < 4; ++kt) wreg[t * 4 + kt] = wp[kt * 4 + kg];
    }
  } else {
    const uint4* wp = (const uint4*)(whT + (gslot * DH + jv) * 64);
#pragma unroll
    for (int mm = 0; mm < 16; ++mm) wreg[mm] = wp[mm];
  }

  if (tid < 64) ((u32*)(lds + HOFF))[tid] = 0u;   // h0 = 0 (f16[128])
  float c = 0.f;
  const float* xb = x + (size_t)b * SEQL * DIN;
  __syncthreads();

  for (int ch = 0; ch < NCHUNK; ++ch) {
    // ---- phase A: xg[t][col] = x_chunk @ wx via MFMA (all 8 waves) ----
#pragma unroll 1
    for (int tt = 0; tt < 4; ++tt) {
      uint4 afr[4];
#pragma unroll
      for (int ko = 0; ko < 4; ++ko) {
        const float4* xp = (const float4*)(xb + (size_t)(ch*TC + tt*16 + r15)*DIN + ko*32 + kg*8);
        float4 v0 = xp[0], v1 = xp[1];
        afr[ko].x = pk2(v0.x, v0.y); afr[ko].y = pk2(v0.z, v0.w);
        afr[ko].z = pk2(v1.x, v1.y); afr[ko].w = pk2(v1.z, v1.w);
      }
#pragma unroll
      for (int nt = 0; nt < 4; ++nt) {
        int n = wv * 64 + nt * 16 + r15;
        f32x4 acc = {0.f, 0.f, 0.f, 0.f};
#pragma unroll
        for (int ko = 0; ko < 4; ++ko) {
          uint4 bf = *(const uint4*)(wxT + n*64 + ko*16 + kg*4);
          acc = MF(afr[ko], bf, acc);
        }
        int t0 = tt*16 + kg*4;
        u32 off = (u32)(n*128 + ((t0*2) ^ ((n & 7) << 4)));
        uint2 pw; pw.x = pk2(acc[0], acc[1]); pw.y = pk2(acc[2], acc[3]);
        *(uint2*)(xgT + off) = pw;
      }
    }
    __syncthreads();

    // ---- phase B: 64 steps; wave-specialized producers + MFMA-wave updater ----
#pragma unroll 1
    for (int m = 0; m < 8; ++m) {
      half8_t xh[4];
      if (mfmaRole) {
#pragma unroll
        for (int g = 0; g < 4; ++g) {
          int cg = g * DH + ju;
          xh[g] = __builtin_bit_cast(half8_t,
              *(const uint4*)(xgT + cg*128 + ((m*16) ^ ((cg & 7) << 4))));
        }
      }
#pragma unroll
      for (int s8 = 0; s8 < 8; ++s8) {
        if (mfmaRole) {
          // gates i,f for cols {j0, j1} via MFMA (A rows all = h)
          const char* hb = lds + HOFF + kg*16;
          uint4 a0 = *(const uint4*)(hb);
          uint4 a1 = *(const uint4*)(hb + 64);
          uint4 a2 = *(const uint4*)(hb + 128);
          uint4 a3 = *(const uint4*)(hb + 192);
          f32x4 z = {0.f, 0.f, 0.f, 0.f};
          f32x4 t0 = z, t1 = z, t2 = z, t3 = z;
          t0 = MF(a0, wreg[0],  t0); t1 = MF(a0, wreg[4],  t1);
          t2 = MF(a0, wreg[8],  t2); t3 = MF(a0, wreg[12], t3);
          t0 = MF(a1, wreg[1],  t0); t1 = MF(a1, wreg[5],  t1);
          t2 = MF(a1, wreg[9],  t2); t3 = MF(a1, wreg[13], t3);
          t0 = MF(a2, wreg[2],  t0); t1 = MF(a2, wreg[6],  t1);
          t2 = MF(a2, wreg[10], t2); t3 = MF(a2, wreg[14], t3);
          t0 = MF(a3, wreg[3],  t0); t1 = MF(a3, wreg[7],  t1);
          t2 = MF(a3, wreg[11], t2); t3 = MF(a3, wreg[15], t3);
          if (kg == 0) {
            int j0 = wv * 16 + r15, j1 = 64 + wv * 16 + r15;
            float2 w0; w0.x = t0[0]; w0.y = t2[0];   // {i[j0], f[j0]}
            float2 w1; w1.x = t1[0]; w1.y = t3[0];   // {i[j1], f[j1]}
            *(float2*)(lds + GOFF + j0*16) = w0;
            *(float2*)(lds + GOFF + j1*16) = w1;
          }
        } else {
          // gates g,o: one full-K column per lane, broadcast h reads
          const u32* hbv = (const u32*)(lds + HOFF);
          float q0 = 0.f, q1 = 0.f, q2 = 0.f, q3 = 0.f;
#pragma unroll
          for (int mm = 0; mm < 16; ++mm) {
            uint4 hv = *(const uint4*)(hbv + mm*4);
            q0 = dot2(wreg[mm].x, hv.x, q0);
            q1 = dot2(wreg[mm].y, hv.y, q1);
            q2 = dot2(wreg[mm].z, hv.z, q2);
            q3 = dot2(wreg[mm].w, hv.w, q3);
          }
          *(float*)(lds + GOFF + jv*16 + gslot*4) = (q0 + q1) + (q2 + q3);
        }
        __syncthreads();
        // ---- updater: MFMA-waves, 2x dup over lanes (l, l+32) ----
        if (mfmaRole) {
          f32x4 gv = *(const f32x4*)(lds + GOFF + ju*16);
          float gi = gv[0] + (float)xh[0][s8];
          float gf = gv[1] + (float)xh[1][s8];
          float gg = gv[2] + (float)xh[2][s8];
          float go = gv[3] + (float)xh[3][s8];
          float si = __builtin_amdgcn_rcpf(1.f + fexp2(gi * -1.442695041f));
          float sf = __builtin_amdgcn_rcpf(1.f + fexp2(gf * -1.442695041f));
          float sg = __builtin_fmaf(2.f,
                       __builtin_amdgcn_rcpf(1.f + fexp2(gg * -2.885390082f)), -1.f);
          float so = __builtin_amdgcn_rcpf(1.f + fexp2(go * -1.442695041f));
          c = __builtin_fmaf(sf, c, si * sg);
          float th = __builtin_fmaf(2.f,
                       __builtin_amdgcn_rcpf(1.f + fexp2(c * -2.885390082f)), -1.f);
          float hval = so * th;
          if (l < 32) *(__fp16*)(lds + HOFF + ju*2) = (__fp16)hval;
        }
        __syncthreads();
      }
    }
  }

  // ---- tail: out[b][n] = h_final @ w_out ----
  if (tid < DH) {
    int n = tid;
    const u32* hf = (const u32*)(lds + HOFF);
    float acc = 0.f;
#pragma unroll 8
    for (int kk = 0; kk < 64; ++kk) {
      half2_t h2v = __builtin_bit_cast(half2_t, hf[kk]);
      acc = __builtin_fmaf((float)h2v[0], w_out[(2*kk)*DH + n],
            __builtin_fmaf((float)h2v[1], w_out[(2*kk+1)*DH + n], acc));
    }
    out[b * DH + n] = acc;
  }
}

extern "C" void kernel_launch(void* const* d_in, const int* in_sizes, int n_in,
                              void* d_out, int out_size, void* d_ws, size_t ws_size,
                              hipStream_t stream) {
  const float* x    = (const float*)d_in[0];
  const float* x2i  = (const float*)d_in[1];
  const float* x2f  = (const float*)d_in[2];
  const float* x2g  = (const float*)d_in[3];
  const float* x2o  = (const float*)d_in[4];
  const float* h2i  = (const float*)d_in[5];
  const float* h2f  = (const float*)d_in[6];
  const float* h2g  = (const float*)d_in[7];
  const float* h2o  = (const float*)d_in[8];
  const float* wout = (const float*)d_in[9];

  u32* wxT = (u32*)d_ws;            // 512*64*4 = 128 KB
  u32* whT = wxT + NC * 64;         // +128 KB

  (void)hipFuncSetAttribute((const void*)lstm_fused,
                            hipFuncAttributeMaxDynamicSharedMemorySize, LDS_TOTAL);

  pack_w<<<64, 512, 0, stream>>>(x2i, x2f, x2g, x2o, h2i, h2f, h2g, h2o, wxT, whT);
  lstm_fused<<<NBATCH, 512, LDS_TOTAL, stream>>>(x, wxT, whT, wout, (float*)d_out);
}

// Round 9
// 384.231 us; speedup vs baseline: 1.1885x; 1.1885x over previous
//
#include <hip/hip_runtime.h>

typedef unsigned int u32;
typedef __fp16 half2_t __attribute__((ext_vector_type(2)));
typedef __fp16 half8_t __attribute__((ext_vector_type(8)));
typedef float  f32x4   __attribute__((ext_vector_type(4)));

#define DIN 128
#define DH  128
#define SEQL 512
#define NBATCH 256
#define NC  512          // 4*DH fused gate columns
#define TC  64           // timesteps per chunk
#define NCHUNK (SEQL/TC) // 8

#define LDS_HOFF 65536   // hbuf byte offset (xgT = 64 KB below it)
#define LDS_TOTAL (65536 + 512)

__device__ __forceinline__ u32 pk2(float a, float b) {
  half2_t h = __builtin_amdgcn_cvt_pkrtz(a, b);
  return __builtin_bit_cast(u32, h);
}

__device__ __forceinline__ float fexp2(float x) {
#if defined(__has_builtin) && __has_builtin(__builtin_amdgcn_exp2f)
  return __builtin_amdgcn_exp2f(x);
#else
  return __builtin_exp2f(x);
#endif
}

__device__ __forceinline__ float dot2(u32 a, u32 b, float c) {
#if defined(__has_builtin) && __has_builtin(__builtin_amdgcn_fdot2)
  return __builtin_amdgcn_fdot2(__builtin_bit_cast(half2_t, a),
                                __builtin_bit_cast(half2_t, b), c, false);
#else
  half2_t ha = __builtin_bit_cast(half2_t, a);
  half2_t hb = __builtin_bit_cast(half2_t, b);
  return c + (float)ha[0]*(float)hb[0] + (float)ha[1]*(float)hb[1];
#endif
}

#if defined(__has_builtin) && __has_builtin(__builtin_amdgcn_update_dpp)
__device__ __forceinline__ float qp_xor1(float v) {   // quad_perm [1,0,3,2]
  return __builtin_bit_cast(float,
      __builtin_amdgcn_update_dpp(0, __builtin_bit_cast(int, v), 0xB1, 0xF, 0xF, true));
}
__device__ __forceinline__ float qp_xor2(float v) {   // quad_perm [2,3,0,1]
  return __builtin_bit_cast(float,
      __builtin_amdgcn_update_dpp(0, __builtin_bit_cast(int, v), 0x4E, 0xF, 0xF, true));
}
#else
__device__ __forceinline__ float qp_xor1(float v) { return __shfl_xor(v, 1, 64); }
__device__ __forceinline__ float qp_xor2(float v) { return __shfl_xor(v, 2, 64); }
#endif

#define MF(A, B, C) __builtin_amdgcn_mfma_f32_16x16x32_f16( \
    __builtin_bit_cast(half8_t, A), __builtin_bit_cast(half8_t, B), C, 0, 0, 0)

// full-K dot2 for gate G (VALU role): 16 dot2 in 4 chains + quad all-reduce
#define DOTG(G, OUT) { \
  float q0=0.f,q1=0.f,q2=0.f,q3=0.f; \
  q0=dot2(wreg[(G)*4+0].x,h0.x,q0); q1=dot2(wreg[(G)*4+0].y,h0.y,q1); \
  q2=dot2(wreg[(G)*4+0].z,h0.z,q2); q3=dot2(wreg[(G)*4+0].w,h0.w,q3); \
  q0=dot2(wreg[(G)*4+1].x,h1.x,q0); q1=dot2(wreg[(G)*4+1].y,h1.y,q1); \
  q2=dot2(wreg[(G)*4+1].z,h1.z,q2); q3=dot2(wreg[(G)*4+1].w,h1.w,q3); \
  q0=dot2(wreg[(G)*4+2].x,h2.x,q0); q1=dot2(wreg[(G)*4+2].y,h2.y,q1); \
  q2=dot2(wreg[(G)*4+2].z,h2.z,q2); q3=dot2(wreg[(G)*4+2].w,h2.w,q3); \
  q0=dot2(wreg[(G)*4+3].x,h3.x,q0); q1=dot2(wreg[(G)*4+3].y,h3.y,q1); \
  q2=dot2(wreg[(G)*4+3].z,h3.z,q2); q3=dot2(wreg[(G)*4+3].w,h3.w,q3); \
  OUT = (q0+q1)+(q2+q3); OUT += qp_xor1(OUT); OUT += qp_xor2(OUT); }

// Pack fused weight matrices into f16-pair (k-pair) column-major images:
// wT[j][kk] = (w[2kk][j], w[2kk+1][j]),  j in [0,512), kk in [0,64)
__global__ void pack_w(const float* __restrict__ x2i, const float* __restrict__ x2f,
                       const float* __restrict__ x2g, const float* __restrict__ x2o,
                       const float* __restrict__ h2i, const float* __restrict__ h2f,
                       const float* __restrict__ h2g, const float* __restrict__ h2o,
                       u32* __restrict__ wxT, u32* __restrict__ whT) {
  int idx = blockIdx.x * blockDim.x + threadIdx.x;   // 0..32767
  if (idx >= NC * 64) return;
  int j = idx >> 6, kk = idx & 63;
  int g = j >> 7, jjj = j & 127;
  const float* wx = (g == 0) ? x2i : (g == 1) ? x2f : (g == 2) ? x2g : x2o;
  const float* wh = (g == 0) ? h2i : (g == 1) ? h2f : (g == 2) ? h2g : h2o;
  wxT[idx] = pk2(wx[(2*kk)*DH + jjj], wx[(2*kk+1)*DH + jjj]);
  whT[idx] = pk2(wh[(2*kk)*DH + jjj], wh[(2*kk+1)*DH + jjj]);
}

// LDS: xgT [512 col][128 B of t, XOR-swizzled f16] = 64 KB ; hbuf [2][128] f16
// Phase B roles: waves 0-3 (one/SIMD) = MFMA, gates for j in [0,64);
//                waves 4-7 (one/SIMD) = VALU dot2, gates for j in [64,128).
// Both roles keep all 4 gates of their j's IN-LANE -> single barrier/step,
// and the two pipes overlap across waves on each SIMD (m114).
__global__ __launch_bounds__(512, 2)
void lstm_fused(
    const float* __restrict__ x, const u32* __restrict__ wxT,
    const u32* __restrict__ whT, const float* __restrict__ w_out,
    float* __restrict__ out) {
  extern __shared__ char lds[];
  char* xgT = lds;

  const int tid = threadIdx.x;
  const int b   = blockIdx.x;
  const int l   = tid & 63, wv = tid >> 6;
  const int kg  = l >> 4, r15 = l & 15;
  const bool mRole = (wv < 4);
  const int kq  = l & 3, jj = l >> 2;
  // hidden index this lane produces gates for:
  const int jb  = mRole ? (wv * 16 + r15) : (64 + (wv - 4) * 16 + jj);

  // Persistent recurrence weights (64 VGPRs), layout per role:
  //  MFMA: wreg[g*4+kt] = B-frag of col jb, k-slice kt*32+kg*8+[0,8)
  //  VALU: wreg[g*4+m]  = col jb, k-quarter kq: u32s kq*16 + m*4 .. +4
  uint4 wreg[16];
  if (mRole) {
#pragma unroll
    for (int g = 0; g < 4; ++g) {
      const uint4* wp = (const uint4*)(whT + (g * DH + jb) * 64);
#pragma unroll
      for (int kt = 0; kt < 4; ++kt) wreg[g * 4 + kt] = wp[kt * 4 + kg];
    }
  } else {
#pragma unroll
    for (int g = 0; g < 4; ++g) {
      const uint4* wp = (const uint4*)(whT + (g * DH + jb) * 64 + kq * 16);
#pragma unroll
      for (int m = 0; m < 4; ++m) wreg[g * 4 + m] = wp[m];
    }
  }

  if (tid < 128) ((u32*)(lds + LDS_HOFF))[tid] = 0u;   // zero both h buffers
  float c = 0.f;
  u32 rdh = LDS_HOFF;          // current h (f16[128])
  u32 wrh = LDS_HOFF + 256;    // next h
  const float* xb = x + (size_t)b * SEQL * DIN;
  __syncthreads();

  for (int ch = 0; ch < NCHUNK; ++ch) {
    // ---- phase A: xg[t][col] = x_chunk @ wx via MFMA (all 8 waves) ----
#pragma unroll 1
    for (int tt = 0; tt < 4; ++tt) {
      uint4 afr[4];
#pragma unroll
      for (int ko = 0; ko < 4; ++ko) {
        const float4* xp = (const float4*)(xb + (size_t)(ch*TC + tt*16 + r15)*DIN + ko*32 + kg*8);
        float4 v0 = xp[0], v1 = xp[1];
        afr[ko].x = pk2(v0.x, v0.y); afr[ko].y = pk2(v0.z, v0.w);
        afr[ko].z = pk2(v1.x, v1.y); afr[ko].w = pk2(v1.z, v1.w);
      }
#pragma unroll
      for (int nt = 0; nt < 4; ++nt) {
        int n = wv * 64 + nt * 16 + r15;
        f32x4 acc = {0.f, 0.f, 0.f, 0.f};
#pragma unroll
        for (int ko = 0; ko < 4; ++ko) {
          uint4 bf = *(const uint4*)(wxT + n*64 + ko*16 + kg*4);
          acc = MF(afr[ko], bf, acc);
        }
        int t0 = tt*16 + kg*4;
        u32 off = (u32)(n*128 + ((t0*2) ^ ((n & 7) << 4)));
        uint2 pw; pw.x = pk2(acc[0], acc[1]); pw.y = pk2(acc[2], acc[3]);
        *(uint2*)(xgT + off) = pw;
      }
    }
    __syncthreads();

    // ---- phase B: 64 steps; MFMA waves (j<64) || VALU waves (j>=64) ----
#pragma unroll 1
    for (int m = 0; m < 8; ++m) {
      half8_t xh[4];
#pragma unroll
      for (int g = 0; g < 4; ++g) {
        int cg = g * DH + jb;
        xh[g] = __builtin_bit_cast(half8_t,
            *(const uint4*)(xgT + cg*128 + ((m*16) ^ ((cg & 7) << 4))));
      }
#pragma unroll
      for (int s8 = 0; s8 < 8; ++s8) {
        float gi, gf, gg, go;
        if (mRole) {
          // h frags: k = kt*32 + kg*8 + [0,8)
          uint4 a0 = *(const uint4*)(lds + rdh +   0 + kg*16);
          uint4 a1 = *(const uint4*)(lds + rdh +  64 + kg*16);
          uint4 a2 = *(const uint4*)(lds + rdh + 128 + kg*16);
          uint4 a3 = *(const uint4*)(lds + rdh + 192 + kg*16);
          f32x4 z = {0.f, 0.f, 0.f, 0.f};
          f32x4 aci = z, acf = z, acg = z, aco = z;
          aci = MF(a0, wreg[0],  aci); acf = MF(a0, wreg[4],  acf);
          acg = MF(a0, wreg[8],  acg); aco = MF(a0, wreg[12], aco);
          aci = MF(a1, wreg[1],  aci); acf = MF(a1, wreg[5],  acf);
          acg = MF(a1, wreg[9],  acg); aco = MF(a1, wreg[13], aco);
          aci = MF(a2, wreg[2],  aci); acf = MF(a2, wreg[6],  acf);
          acg = MF(a2, wreg[10], acg); aco = MF(a2, wreg[14], aco);
          aci = MF(a3, wreg[3],  aci); acf = MF(a3, wreg[7],  acf);
          acg = MF(a3, wreg[11], acg); aco = MF(a3, wreg[15], aco);
          gi = aci[0] + (float)xh[0][s8];
          gf = acf[0] + (float)xh[1][s8];
          gg = acg[0] + (float)xh[2][s8];
          go = aco[0] + (float)xh[3][s8];
        } else {
          // h frags: k = kq*32 + [0,32)
          uint4 h0 = *(const uint4*)(lds + rdh + kq*64);
          uint4 h1 = *(const uint4*)(lds + rdh + kq*64 + 16);
          uint4 h2 = *(const uint4*)(lds + rdh + kq*64 + 32);
          uint4 h3 = *(const uint4*)(lds + rdh + kq*64 + 48);
          float r0, r1, r2, r3;
          DOTG(0, r0) DOTG(1, r1) DOTG(2, r2) DOTG(3, r3)
          gi = r0 + (float)xh[0][s8];
          gf = r1 + (float)xh[1][s8];
          gg = r2 + (float)xh[2][s8];
          go = r3 + (float)xh[3][s8];
        }
        float si = __builtin_amdgcn_rcpf(1.f + fexp2(gi * -1.442695041f));
        float sf = __builtin_amdgcn_rcpf(1.f + fexp2(gf * -1.442695041f));
        float sg = __builtin_fmaf(2.f,
                     __builtin_amdgcn_rcpf(1.f + fexp2(gg * -2.885390082f)), -1.f);
        float so = __builtin_amdgcn_rcpf(1.f + fexp2(go * -1.442695041f));
        c = __builtin_fmaf(sf, c, si * sg);
        float th = __builtin_fmaf(2.f,
                     __builtin_amdgcn_rcpf(1.f + fexp2(c * -2.885390082f)), -1.f);
        float hval = so * th;
        bool writer = mRole ? (l < 16) : (kq == 0);
        if (writer) *(__fp16*)(lds + wrh + jb * 2) = (__fp16)hval;
        rdh ^= 256; wrh ^= 256;
        __syncthreads();
      }
    }
  }

  // ---- tail: out[b][n] = h_final @ w_out ----
  if (tid < DH) {
    int n = tid;
    const u32* hf = (const u32*)(lds + rdh);   // final h (f16 pairs)
    float acc = 0.f;
#pragma unroll 8
    for (int kk = 0; kk < 64; ++kk) {
      half2_t h2v = __builtin_bit_cast(half2_t, hf[kk]);
      acc = __builtin_fmaf((float)h2v[0], w_out[(2*kk)*DH + n],
            __builtin_fmaf((float)h2v[1], w_out[(2*kk+1)*DH + n], acc));
    }
    out[b * DH + n] = acc;
  }
}

extern "C" void kernel_launch(void* const* d_in, const int* in_sizes, int n_in,
                              void* d_out, int out_size, void* d_ws, size_t ws_size,
                              hipStream_t stream) {
  const float* x    = (const float*)d_in[0];
  const float* x2i  = (const float*)d_in[1];
  const float* x2f  = (const float*)d_in[2];
  const float* x2g  = (const float*)d_in[3];
  const float* x2o  = (const float*)d_in[4];
  const float* h2i  = (const float*)d_in[5];
  const float* h2f  = (const float*)d_in[6];
  const float* h2g  = (const float*)d_in[7];
  const float* h2o  = (const float*)d_in[8];
  const float* wout = (const float*)d_in[9];

  u32* wxT = (u32*)d_ws;            // 512*64*4 = 128 KB
  u32* whT = wxT + NC * 64;         // +128 KB

  (void)hipFuncSetAttribute((const void*)lstm_fused,
                            hipFuncAttributeMaxDynamicSharedMemorySize, LDS_TOTAL);

  pack_w<<<64, 512, 0, stream>>>(x2i, x2f, x2g, x2o, h2i, h2f, h2g, h2o, wxT, whT);
  lstm_fused<<<NBATCH, 512, LDS_TOTAL, stream>>>(x, wxT, whT, wout, (float*)d_out);
}

// Round 10
// 340.340 us; speedup vs baseline: 1.3418x; 1.1290x over previous
//
#include <hip/hip_runtime.h>

typedef unsigned int u32;
typedef __fp16 half2_t __attribute__((ext_vector_type(2)));
typedef __fp16 half8_t __attribute__((ext_vector_type(8)));
typedef float  f32x4   __attribute__((ext_vector_type(4)));

#define DIN 128
#define DH  128
#define SEQL 512
#define NBATCH 256
#define NC  512          // 4*DH fused gate columns
#define TC  64           // timesteps per chunk
#define NCHUNK (SEQL/TC) // 8

#define HOFF 131072              // hbuf after 2 xgT buffers
#define LDS_TOTAL (131072 + 512)

__device__ __forceinline__ u32 pk2(float a, float b) {
  half2_t h = __builtin_amdgcn_cvt_pkrtz(a, b);
  return __builtin_bit_cast(u32, h);
}

__device__ __forceinline__ float fexp2(float x) {
#if defined(__has_builtin) && __has_builtin(__builtin_amdgcn_exp2f)
  return __builtin_amdgcn_exp2f(x);
#else
  return __builtin_exp2f(x);
#endif
}

// raw step barrier: publish LDS writes, do NOT drain vmcnt (keeps phase-A
// prefetch loads in flight across the recurrence barriers)
__device__ __forceinline__ void step_barrier() {
  asm volatile("s_waitcnt lgkmcnt(0)" ::: "memory");
  __builtin_amdgcn_s_barrier();
  asm volatile("" ::: "memory");
}

#define MF(A, B, C) __builtin_amdgcn_mfma_f32_16x16x32_f16( \
    __builtin_bit_cast(half8_t, A), __builtin_bit_cast(half8_t, B), C, 0, 0, 0)

// Pack fused weight matrices into f16-pair (k-pair) column-major images:
// wT[j][kk] = (w[2kk][j], w[2kk+1][j]),  j in [0,512), kk in [0,64)
__global__ void pack_w(const float* __restrict__ x2i, const float* __restrict__ x2f,
                       const float* __restrict__ x2g, const float* __restrict__ x2o,
                       const float* __restrict__ h2i, const float* __restrict__ h2f,
                       const float* __restrict__ h2g, const float* __restrict__ h2o,
                       u32* __restrict__ wxT, u32* __restrict__ whT) {
  int idx = blockIdx.x * blockDim.x + threadIdx.x;   // 0..32767
  if (idx >= NC * 64) return;
  int j = idx >> 6, kk = idx & 63;
  int g = j >> 7, jjj = j & 127;
  const float* wx = (g == 0) ? x2i : (g == 1) ? x2f : (g == 2) ? x2g : x2o;
  const float* wh = (g == 0) ? h2i : (g == 1) ? h2f : (g == 2) ? h2g : h2o;
  wxT[idx] = pk2(wx[(2*kk)*DH + jjj], wx[(2*kk+1)*DH + jjj]);
  whT[idx] = pk2(wh[(2*kk)*DH + jjj], wh[(2*kk+1)*DH + jjj]);
}

// LDS: xgT[2] double buffer (2 x 64 KB, [col][128 B of t] XOR-swizzled f16),
//      hbuf [2][128] f16 at HOFF.
// Main loop: phase B (64 recurrence steps) on xgT[cur] while building
// xgT[cur^1] for the next chunk (loads on even m-groups, MFMA+store on odd).
__global__ __launch_bounds__(512, 2)
void lstm_fused(
    const float* __restrict__ x, const u32* __restrict__ wxT,
    const u32* __restrict__ whT, const float* __restrict__ w_out,
    float* __restrict__ out) {
  extern __shared__ char lds[];

  const int tid = threadIdx.x;
  const int b   = blockIdx.x;
  const int l   = tid & 63, wv = tid >> 6;
  const int kg  = l >> 4, r15 = l & 15;
  const int j   = wv * 16 + r15;   // hidden index this lane owns

  // Recurrence B-frags: bw[g][kt] = whT[(g*128+j)*64][kt*4+kg]  (64 VGPRs)
  uint4 bw[4][4];
#pragma unroll
  for (int g = 0; g < 4; ++g) {
    const uint4* wp = (const uint4*)(whT + (g * DH + j) * 64);
#pragma unroll
    for (int kt = 0; kt < 4; ++kt) bw[g][kt] = wp[kt * 4 + kg];
  }

  if (tid < 128) ((u32*)(lds + HOFF))[tid] = 0u;   // zero both h buffers
  float c = 0.f;
  u32 rdh = HOFF;          // current h (f16[128])
  u32 wrh = HOFF + 256;    // next h
  const float* xb = x + (size_t)b * SEQL * DIN;
  __syncthreads();

  // ---- phase A for chunk 0 (standalone) ----
#pragma unroll 1
  for (int tt = 0; tt < 4; ++tt) {
    uint4 afr[4];
#pragma unroll
    for (int ko = 0; ko < 4; ++ko) {
      const float4* xp = (const float4*)(xb + (size_t)(tt*16 + r15)*DIN + ko*32 + kg*8);
      float4 v0 = xp[0], v1 = xp[1];
      afr[ko].x = pk2(v0.x, v0.y); afr[ko].y = pk2(v0.z, v0.w);
      afr[ko].z = pk2(v1.x, v1.y); afr[ko].w = pk2(v1.z, v1.w);
    }
#pragma unroll
    for (int nt = 0; nt < 4; ++nt) {
      int n = wv * 64 + nt * 16 + r15;
      f32x4 acc = {0.f, 0.f, 0.f, 0.f};
#pragma unroll
      for (int ko = 0; ko < 4; ++ko) {
        uint4 bf = *(const uint4*)(wxT + n*64 + ko*16 + kg*4);
        acc = MF(afr[ko], bf, acc);
      }
      int t0 = tt*16 + kg*4;
      u32 off = (u32)(n*128 + ((t0*2) ^ ((n & 7) << 4)));
      uint2 pw; pw.x = pk2(acc[0], acc[1]); pw.y = pk2(acc[2], acc[3]);
      *(uint2*)(lds + off) = pw;   // buffer 0
    }
  }
  __syncthreads();

  int cur = 0;
#pragma unroll 1
  for (int ch = 0; ch < NCHUNK; ++ch) {
    char* xgC = lds + cur * 65536;
    char* xgN = lds + (cur ^ 1) * 65536;
    const bool doA = (ch + 1 < NCHUNK);
    float4 lv[8];   // in-flight phase-A loads (issued even m, used odd m)

#pragma unroll 1
    for (int m = 0; m < 8; ++m) {
      // xg for col j of each gate, timesteps [8m, 8m+8)
      half8_t xh[4];
#pragma unroll
      for (int g = 0; g < 4; ++g) {
        int cg = g * DH + j;
        xh[g] = __builtin_bit_cast(half8_t,
            *(const uint4*)(xgC + cg*128 + ((m*16) ^ ((cg & 7) << 4))));
      }

      // ---- interleaved phase A for chunk ch+1 (tile tt = m>>1) ----
      if (doA) {
        int tt = m >> 1;
        if ((m & 1) == 0) {
          // issue 8 global float4 loads; they stay in flight across the
          // next 8 steps' raw barriers (no vmcnt drain)
          const float* xr = xb + (size_t)((ch+1)*TC + tt*16 + r15)*DIN + kg*8;
#pragma unroll
          for (int ko = 0; ko < 4; ++ko) {
            const float4* xp = (const float4*)(xr + ko*32);
            lv[2*ko]   = xp[0];
            lv[2*ko+1] = xp[1];
          }
        } else {
          uint4 afr[4];
#pragma unroll
          for (int ko = 0; ko < 4; ++ko) {
            float4 v0 = lv[2*ko], v1 = lv[2*ko+1];
            afr[ko].x = pk2(v0.x, v0.y); afr[ko].y = pk2(v0.z, v0.w);
            afr[ko].z = pk2(v1.x, v1.y); afr[ko].w = pk2(v1.z, v1.w);
          }
#pragma unroll
          for (int nt = 0; nt < 4; ++nt) {
            int n = wv * 64 + nt * 16 + r15;
            f32x4 acc = {0.f, 0.f, 0.f, 0.f};
#pragma unroll
            for (int ko = 0; ko < 4; ++ko) {
              uint4 bf = *(const uint4*)(wxT + n*64 + ko*16 + kg*4);
              acc = MF(afr[ko], bf, acc);
            }
            int t0 = tt*16 + kg*4;
            u32 off = (u32)(n*128 + ((t0*2) ^ ((n & 7) << 4)));
            uint2 pw; pw.x = pk2(acc[0], acc[1]); pw.y = pk2(acc[2], acc[3]);
            *(uint2*)(xgN + off) = pw;
          }
        }
      }

      // ---- 8 recurrence steps ----
#pragma unroll
      for (int s8 = 0; s8 < 8; ++s8) {
        uint4 a0 = *(const uint4*)(lds + rdh +   0 + kg*16);
        uint4 a1 = *(const uint4*)(lds + rdh +  64 + kg*16);
        uint4 a2 = *(const uint4*)(lds + rdh + 128 + kg*16);
        uint4 a3 = *(const uint4*)(lds + rdh + 192 + kg*16);
        f32x4 z = {0.f, 0.f, 0.f, 0.f};
        f32x4 aci = z, acf = z, acg = z, aco = z;
        aci = MF(a0, bw[0][0], aci); acf = MF(a0, bw[1][0], acf);
        acg = MF(a0, bw[2][0], acg); aco = MF(a0, bw[3][0], aco);
        aci = MF(a1, bw[0][1], aci); acf = MF(a1, bw[1][1], acf);
        acg = MF(a1, bw[2][1], acg); aco = MF(a1, bw[3][1], aco);
        aci = MF(a2, bw[0][2], aci); acf = MF(a2, bw[1][2], acf);
        acg = MF(a2, bw[2][2], acg); aco = MF(a2, bw[3][2], aco);
        aci = MF(a3, bw[0][3], aci); acf = MF(a3, bw[1][3], acf);
        acg = MF(a3, bw[2][3], acg); aco = MF(a3, bw[3][3], aco);
        float gi = aci[0] + (float)xh[0][s8];
        float gf = acf[0] + (float)xh[1][s8];
        float gg = acg[0] + (float)xh[2][s8];
        float go = aco[0] + (float)xh[3][s8];
        float si = __builtin_amdgcn_rcpf(1.f + fexp2(gi * -1.442695041f));
        float sf = __builtin_amdgcn_rcpf(1.f + fexp2(gf * -1.442695041f));
        float sg = __builtin_fmaf(2.f,
                     __builtin_amdgcn_rcpf(1.f + fexp2(gg * -2.885390082f)), -1.f);
        float so = __builtin_amdgcn_rcpf(1.f + fexp2(go * -1.442695041f));
        c = __builtin_fmaf(sf, c, si * sg);
        float th = __builtin_fmaf(2.f,
                     __builtin_amdgcn_rcpf(1.f + fexp2(c * -2.885390082f)), -1.f);
        float hval = so * th;
        if (l < 16) *(__fp16*)(lds + wrh + j * 2) = (__fp16)hval;
        step_barrier();
        rdh ^= 256; wrh ^= 256;
      }
    }
    cur ^= 1;
  }

  // ---- tail: out[b][n] = h_final @ w_out ----
  if (tid < DH) {
    int n = tid;
    const u32* hf = (const u32*)(lds + rdh);   // final h (f16 pairs)
    float acc = 0.f;
#pragma unroll 8
    for (int kk = 0; kk < 64; ++kk) {
      half2_t h2v = __builtin_bit_cast(half2_t, hf[kk]);
      acc = __builtin_fmaf((float)h2v[0], w_out[(2*kk)*DH + n],
            __builtin_fmaf((float)h2v[1], w_out[(2*kk+1)*DH + n], acc));
    }
    out[b * DH + n] = acc;
  }
}

extern "C" void kernel_launch(void* const* d_in, const int* in_sizes, int n_in,
                              void* d_out, int out_size, void* d_ws, size_t ws_size,
                              hipStream_t stream) {
  const float* x    = (const float*)d_in[0];
  const float* x2i  = (const float*)d_in[1];
  const float* x2f  = (const float*)d_in[2];
  const float* x2g  = (const float*)d_in[3];
  const float* x2o  = (const float*)d_in[4];
  const float* h2i  = (const float*)d_in[5];
  const float* h2f  = (const float*)d_in[6];
  const float* h2g  = (const float*)d_in[7];
  const float* h2o  = (const float*)d_in[8];
  const float* wout = (const float*)d_in[9];

  u32* wxT = (u32*)d_ws;            // 512*64*4 = 128 KB
  u32* whT = wxT + NC * 64;         // +128 KB

  (void)hipFuncSetAttribute((const void*)lstm_fused,
                            hipFuncAttributeMaxDynamicSharedMemorySize, LDS_TOTAL);

  pack_w<<<64, 512, 0, stream>>>(x2i, x2f, x2g, x2o, h2i, h2f, h2g, h2o, wxT, whT);
  lstm_fused<<<NBATCH, 512, LDS_TOTAL, stream>>>(x, wxT, whT, wout, (float*)d_out);
}

// Round 11
// 281.561 us; speedup vs baseline: 1.6219x; 1.2088x over previous
//
#include <hip/hip_runtime.h>

typedef unsigned int u32;
typedef __fp16 half2_t __attribute__((ext_vector_type(2)));
typedef __fp16 half8_t __attribute__((ext_vector_type(8)));
typedef float  f32x4   __attribute__((ext_vector_type(4)));

#define DIN 128
#define DH  128
#define SEQL 512
#define NBATCH 256
#define NC  512          // 4*DH fused gate columns
#define TC  64           // timesteps per chunk
#define NCHUNK (SEQL/TC) // 8

#define LDS_HOFF 65536   // hbuf byte offset (xgT = 64 KB below it)
#define LDS_TOTAL (65536 + 512)

__device__ __forceinline__ u32 pk2(float a, float b) {
  half2_t h = __builtin_amdgcn_cvt_pkrtz(a, b);
  return __builtin_bit_cast(u32, h);
}

__device__ __forceinline__ float fexp2(float x) {
#if defined(__has_builtin) && __has_builtin(__builtin_amdgcn_exp2f)
  return __builtin_amdgcn_exp2f(x);
#else
  return __builtin_exp2f(x);
#endif
}

#define MF(A, B, C) __builtin_amdgcn_mfma_f32_16x16x32_f16( \
    __builtin_bit_cast(half8_t, A), __builtin_bit_cast(half8_t, B), C, 0, 0, 0)

// Pack fused weight matrices into f16-pair (k-pair) column-major images,
// PRE-SCALED by the exp2 conversion constants so the recurrence needs no
// per-step multiply:  i,f,o cols * -log2(e), g cols * -2*log2(e).
// wT[j][kk] = (s*w[2kk][j], s*w[2kk+1][j]),  j in [0,512), kk in [0,64)
__global__ void pack_w(const float* __restrict__ x2i, const float* __restrict__ x2f,
                       const float* __restrict__ x2g, const float* __restrict__ x2o,
                       const float* __restrict__ h2i, const float* __restrict__ h2f,
                       const float* __restrict__ h2g, const float* __restrict__ h2o,
                       u32* __restrict__ wxT, u32* __restrict__ whT) {
  int idx = blockIdx.x * blockDim.x + threadIdx.x;   // 0..32767
  if (idx >= NC * 64) return;
  int j = idx >> 6, kk = idx & 63;
  int g = j >> 7, jjj = j & 127;
  const float* wx = (g == 0) ? x2i : (g == 1) ? x2f : (g == 2) ? x2g : x2o;
  const float* wh = (g == 0) ? h2i : (g == 1) ? h2f : (g == 2) ? h2g : h2o;
  float s = (g == 2) ? -2.885390082f : -1.442695041f;
  wxT[idx] = pk2(s * wx[(2*kk)*DH + jjj], s * wx[(2*kk+1)*DH + jjj]);
  whT[idx] = pk2(s * wh[(2*kk)*DH + jjj], s * wh[(2*kk+1)*DH + jjj]);
}

// LDS: xgT [512 col][128 B of t, XOR-swizzled f16] = 64 KB ; hbuf [2][128] f16
__global__ __launch_bounds__(512, 2)
void lstm_fused(
    const float* __restrict__ x, const u32* __restrict__ wxT,
    const u32* __restrict__ whT, const float* __restrict__ w_out,
    float* __restrict__ out) {
  extern __shared__ char lds[];
  char* xgT = lds;

  const int tid = threadIdx.x;
  const int b   = blockIdx.x;
  const int l   = tid & 63, wv = tid >> 6;
  const int kg  = l >> 4, r15 = l & 15;
  const int j   = wv * 16 + r15;   // hidden index this lane owns

  // Recurrence B-frags: bw[g][kt] = whT[(g*128+j)*64][kt*4+kg]  (64 VGPRs)
  uint4 bw[4][4];
#pragma unroll
  for (int g = 0; g < 4; ++g) {
    const uint4* wp = (const uint4*)(whT + (g * DH + j) * 64);
#pragma unroll
    for (int kt = 0; kt < 4; ++kt) bw[g][kt] = wp[kt * 4 + kg];
  }

  if (tid < 128) ((u32*)(lds + LDS_HOFF))[tid] = 0u;   // zero both h buffers
  float c = 0.f;
  u32 rdh = LDS_HOFF;          // current h (f16[128])
  u32 wrh = LDS_HOFF + 256;    // next h
  const float* xb = x + (size_t)b * SEQL * DIN;

  // persistent zero accumulator seed: 4 VGPRs of 0.0, never rewritten.
  // Every gate chain starts as MF(a0, b, Z) so no per-step acc init movs.
  const f32x4 Z = {0.f, 0.f, 0.f, 0.f};

  __syncthreads();

  for (int ch = 0; ch < NCHUNK; ++ch) {
    // ---- phase A: xg[t][col] = x_chunk @ wx via MFMA, A-frags from global ----
#pragma unroll 1
    for (int tt = 0; tt < 4; ++tt) {
      uint4 afr[4];
#pragma unroll
      for (int ko = 0; ko < 4; ++ko) {
        const float4* xp = (const float4*)(xb + (size_t)(ch*TC + tt*16 + r15)*DIN + ko*32 + kg*8);
        float4 v0 = xp[0], v1 = xp[1];
        afr[ko].x = pk2(v0.x, v0.y); afr[ko].y = pk2(v0.z, v0.w);
        afr[ko].z = pk2(v1.x, v1.y); afr[ko].w = pk2(v1.z, v1.w);
      }
#pragma unroll
      for (int nt = 0; nt < 4; ++nt) {
        int n = wv * 64 + nt * 16 + r15;
        f32x4 acc = MF(afr[0], *(const uint4*)(wxT + n*64 + 0*16 + kg*4), Z);
#pragma unroll
        for (int ko = 1; ko < 4; ++ko) {
          uint4 bf = *(const uint4*)(wxT + n*64 + ko*16 + kg*4);
          acc = MF(afr[ko], bf, acc);
        }
        // store C: col n, t0 = tt*16+kg*4 .. +4, into [col][t] XOR-swizzled
        int t0 = tt*16 + kg*4;
        u32 off = (u32)(n*128 + ((t0*2) ^ ((n & 7) << 4)));
        uint2 pw; pw.x = pk2(acc[0], acc[1]); pw.y = pk2(acc[2], acc[3]);
        *(uint2*)(xgT + off) = pw;
      }
    }
    __syncthreads();

    // ---- phase B: 64 sequential steps, MFMA recurrence (M=1 padded to 16) ----
#pragma unroll 1
    for (int m = 0; m < 8; ++m) {
      // xg for col j of each gate, timesteps [8m, 8m+8)  (pre-scaled)
      half8_t xh[4];
#pragma unroll
      for (int g = 0; g < 4; ++g) {
        int cg = g * DH + j;
        xh[g] = __builtin_bit_cast(half8_t,
            *(const uint4*)(xgT + cg*128 + ((m*16) ^ ((cg & 7) << 4))));
      }
#pragma unroll
      for (int s8 = 0; s8 < 8; ++s8) {
        // A-frags: all 16 "rows" = h (broadcast); lane reads h[kt*32+kg*8 .. +8]
        uint4 a0 = *(const uint4*)(lds + rdh +   0 + kg*16);
        uint4 a1 = *(const uint4*)(lds + rdh +  64 + kg*16);
        uint4 a2 = *(const uint4*)(lds + rdh + 128 + kg*16);
        uint4 a3 = *(const uint4*)(lds + rdh + 192 + kg*16);
        f32x4 aci = MF(a0, bw[0][0], Z);
        f32x4 acf = MF(a0, bw[1][0], Z);
        f32x4 acg = MF(a0, bw[2][0], Z);
        f32x4 aco = MF(a0, bw[3][0], Z);
        aci = MF(a1, bw[0][1], aci); acf = MF(a1, bw[1][1], acf);
        acg = MF(a1, bw[2][1], acg); aco = MF(a1, bw[3][1], aco);
        aci = MF(a2, bw[0][2], aci); acf = MF(a2, bw[1][2], acf);
        acg = MF(a2, bw[2][2], acg); aco = MF(a2, bw[3][2], aco);
        aci = MF(a3, bw[0][3], aci); acf = MF(a3, bw[1][3], acf);
        acg = MF(a3, bw[2][3], acg); aco = MF(a3, bw[3][3], aco);
        // gates arrive pre-scaled-negated: sigma = rcp(1+exp2(gate))
        float gi = aci[0] + (float)xh[0][s8];
        float gf = acf[0] + (float)xh[1][s8];
        float gg = acg[0] + (float)xh[2][s8];
        float go = aco[0] + (float)xh[3][s8];
        float si = __builtin_amdgcn_rcpf(1.f + fexp2(gi));
        float sf = __builtin_amdgcn_rcpf(1.f + fexp2(gf));
        float sg = __builtin_fmaf(2.f, __builtin_amdgcn_rcpf(1.f + fexp2(gg)), -1.f);
        float so = __builtin_amdgcn_rcpf(1.f + fexp2(go));
        c = __builtin_fmaf(sf, c, si * sg);
        float th = __builtin_fmaf(2.f,
                     __builtin_amdgcn_rcpf(1.f + fexp2(c * -2.885390082f)), -1.f);
        float hval = so * th;
        if (l < 16) *(__fp16*)(lds + wrh + j * 2) = (__fp16)hval;
        u32 tswap = rdh; rdh = wrh; wrh = tswap;
        __syncthreads();
      }
    }
  }

  // ---- tail: out[b][n] = h_final @ w_out ----
  if (tid < DH) {
    int n = tid;
    const u32* hf = (const u32*)(lds + rdh);   // final h (f16 pairs)
    float acc = 0.f;
#pragma unroll 8
    for (int kk = 0; kk < 64; ++kk) {
      half2_t h2v = __builtin_bit_cast(half2_t, hf[kk]);
      acc = __builtin_fmaf((float)h2v[0], w_out[(2*kk)*DH + n],
            __builtin_fmaf((float)h2v[1], w_out[(2*kk+1)*DH + n], acc));
    }
    out[b * DH + n] = acc;
  }
}

extern "C" void kernel_launch(void* const* d_in, const int* in_sizes, int n_in,
                              void* d_out, int out_size, void* d_ws, size_t ws_size,
                              hipStream_t stream) {
  const float* x    = (const float*)d_in[0];
  const float* x2i  = (const float*)d_in[1];
  const float* x2f  = (const float*)d_in[2];
  const float* x2g  = (const float*)d_in[3];
  const float* x2o  = (const float*)d_in[4];
  const float* h2i  = (const float*)d_in[5];
  const float* h2f  = (const float*)d_in[6];
  const float* h2g  = (const float*)d_in[7];
  const float* h2o  = (const float*)d_in[8];
  const float* wout = (const float*)d_in[9];

  u32* wxT = (u32*)d_ws;            // 512*64*4 = 128 KB
  u32* whT = wxT + NC * 64;         // +128 KB

  (void)hipFuncSetAttribute((const void*)lstm_fused,
                            hipFuncAttributeMaxDynamicSharedMemorySize, LDS_TOTAL);

  pack_w<<<64, 512, 0, stream>>>(x2i, x2f, x2g, x2o, h2i, h2f, h2g, h2o, wxT, whT);
  lstm_fused<<<NBATCH, 512, LDS_TOTAL, stream>>>(x, wxT, whT, wout, (float*)d_out);
}

// Round 12
// 265.253 us; speedup vs baseline: 1.7217x; 1.0615x over previous
//
#include <hip/hip_runtime.h>

typedef unsigned int u32;
typedef __fp16 half2_t __attribute__((ext_vector_type(2)));
typedef __fp16 half8_t __attribute__((ext_vector_type(8)));
typedef float  f32x4   __attribute__((ext_vector_type(4)));

#define DIN 128
#define DH  128
#define SEQL 512
#define NBATCH 256
#define NC  512          // 4*DH fused gate columns
#define TC  64           // timesteps per chunk
#define NCHUNK (SEQL/TC) // 8

#define HOFF 131072              // hbuf after 2 xgT buffers (2 x 64 KB)
#define LDS_TOTAL (131072 + 512)

__device__ __forceinline__ u32 pk2(float a, float b) {
  half2_t h = __builtin_amdgcn_cvt_pkrtz(a, b);
  return __builtin_bit_cast(u32, h);
}

__device__ __forceinline__ float fexp2(float x) {
#if defined(__has_builtin) && __has_builtin(__builtin_amdgcn_exp2f)
  return __builtin_amdgcn_exp2f(x);
#else
  return __builtin_exp2f(x);
#endif
}

#define MF(A, B, C) __builtin_amdgcn_mfma_f32_16x16x32_f16( \
    __builtin_bit_cast(half8_t, A), __builtin_bit_cast(half8_t, B), C, 0, 0, 0)

// Pack fused weight matrices into f16-pair (k-pair) column-major images,
// PRE-SCALED by the exp2 conversion constants (i,f,o: -log2e; g: -2log2e).
__global__ void pack_w(const float* __restrict__ x2i, const float* __restrict__ x2f,
                       const float* __restrict__ x2g, const float* __restrict__ x2o,
                       const float* __restrict__ h2i, const float* __restrict__ h2f,
                       const float* __restrict__ h2g, const float* __restrict__ h2o,
                       u32* __restrict__ wxT, u32* __restrict__ whT) {
  int idx = blockIdx.x * blockDim.x + threadIdx.x;   // 0..32767
  if (idx >= NC * 64) return;
  int j = idx >> 6, kk = idx & 63;
  int g = j >> 7, jjj = j & 127;
  const float* wx = (g == 0) ? x2i : (g == 1) ? x2f : (g == 2) ? x2g : x2o;
  const float* wh = (g == 0) ? h2i : (g == 1) ? h2f : (g == 2) ? h2g : h2o;
  float s = (g == 2) ? -2.885390082f : -1.442695041f;
  wxT[idx] = pk2(s * wx[(2*kk)*DH + jjj], s * wx[(2*kk+1)*DH + jjj]);
  whT[idx] = pk2(s * wh[(2*kk)*DH + jjj], s * wh[(2*kk+1)*DH + jjj]);
}

// LDS: xgT[2] double buffer ([col][128 B of t] XOR-swizzled f16) + hbuf [2][128].
// Phase A for chunk ch+1 is interleaved INTO chunk ch's 64 recurrence steps:
//   even m-group: s8=0 issue 8 x-loads (return < 1 step, drained by barrier);
//                 s8=2,3 convert to f16 A-frags.
//   odd  m-group: 2 A-MFMA per step from persistent bfA regs; store per n-tile.
__global__ __launch_bounds__(512, 2)
void lstm_fused(
    const float* __restrict__ x, const u32* __restrict__ wxT,
    const u32* __restrict__ whT, const float* __restrict__ w_out,
    float* __restrict__ out) {
  extern __shared__ char lds[];

  const int tid = threadIdx.x;
  const int b   = blockIdx.x;
  const int l   = tid & 63, wv = tid >> 6;
  const int kg  = l >> 4, r15 = l & 15;
  const int j   = wv * 16 + r15;   // hidden index this lane owns

  // Recurrence B-frags: bw[g][kt] = whT[(g*128+j)*64][kt*4+kg]  (64 VGPRs)
  uint4 bw[4][4];
#pragma unroll
  for (int g = 0; g < 4; ++g) {
    const uint4* wp = (const uint4*)(whT + (g * DH + j) * 64);
#pragma unroll
    for (int kt = 0; kt < 4; ++kt) bw[g][kt] = wp[kt * 4 + kg];
  }
  // Phase-A B-frags (persistent, 64 VGPRs): this wave's 4 n-tiles
  uint4 bfA[4][4];
#pragma unroll
  for (int nt = 0; nt < 4; ++nt) {
    int n = wv * 64 + nt * 16 + r15;
#pragma unroll
    for (int ko = 0; ko < 4; ++ko)
      bfA[nt][ko] = *(const uint4*)(wxT + n*64 + ko*16 + kg*4);
  }

  if (tid < 128) ((u32*)(lds + HOFF))[tid] = 0u;   // zero both h buffers
  float c = 0.f;
  u32 rdh = HOFF;          // current h (f16[128])
  u32 wrh = HOFF + 256;    // next h
  const float* xb = x + (size_t)b * SEQL * DIN;
  const f32x4 Z = {0.f, 0.f, 0.f, 0.f};
  __syncthreads();

  // ---- standalone phase A for chunk 0 -> buffer 0 ----
#pragma unroll 1
  for (int tt = 0; tt < 4; ++tt) {
    uint4 afr0[4];
#pragma unroll
    for (int ko = 0; ko < 4; ++ko) {
      const float4* xp = (const float4*)(xb + (size_t)(tt*16 + r15)*DIN + ko*32 + kg*8);
      float4 v0 = xp[0], v1 = xp[1];
      afr0[ko].x = pk2(v0.x, v0.y); afr0[ko].y = pk2(v0.z, v0.w);
      afr0[ko].z = pk2(v1.x, v1.y); afr0[ko].w = pk2(v1.z, v1.w);
    }
#pragma unroll
    for (int nt = 0; nt < 4; ++nt) {
      int n = wv * 64 + nt * 16 + r15;
      f32x4 acc = MF(afr0[0], bfA[nt][0], Z);
      acc = MF(afr0[1], bfA[nt][1], acc);
      acc = MF(afr0[2], bfA[nt][2], acc);
      acc = MF(afr0[3], bfA[nt][3], acc);
      int t0 = tt*16 + kg*4;
      u32 off = (u32)(n*128 + ((t0*2) ^ ((n & 7) << 4)));
      uint2 pw; pw.x = pk2(acc[0], acc[1]); pw.y = pk2(acc[2], acc[3]);
      *(uint2*)(lds + off) = pw;
    }
  }
  __syncthreads();

  int cur = 0;
#pragma unroll 1
  for (int ch = 0; ch < NCHUNK; ++ch) {
    char* xgC = lds + cur * 65536;
    char* xgN = lds + (cur ^ 1) * 65536;
    const bool doA = (ch + 1 < NCHUNK);
    float4 lv[8];    // staged x loads (even m)
    uint4  afr[4];   // f16 A-frags   (built even m, consumed odd m)
    f32x4  aacc;     // A accumulator (odd m, spans 2 steps)

#pragma unroll 1
    for (int m = 0; m < 8; ++m) {
      const int tt = m >> 1;
      // xg for col j of each gate, timesteps [8m, 8m+8)  (pre-scaled)
      half8_t xh[4];
#pragma unroll
      for (int g = 0; g < 4; ++g) {
        int cg = g * DH + j;
        xh[g] = __builtin_bit_cast(half8_t,
            *(const uint4*)(xgC + cg*128 + ((m*16) ^ ((cg & 7) << 4))));
      }
#pragma unroll
      for (int s8 = 0; s8 < 8; ++s8) {
        // ---- interleaved phase A (chunk ch+1) ----
        if (doA) {
          if ((m & 1) == 0) {
            if (s8 == 0) {
              const float* xr = xb + (size_t)((ch+1)*TC + tt*16 + r15)*DIN + kg*8;
#pragma unroll
              for (int ko = 0; ko < 4; ++ko) {
                const float4* xp = (const float4*)(xr + ko*32);
                lv[2*ko]   = xp[0];
                lv[2*ko+1] = xp[1];
              }
            }
            if (s8 == 2) {
#pragma unroll
              for (int ko = 0; ko < 2; ++ko) {
                float4 v0 = lv[2*ko], v1 = lv[2*ko+1];
                afr[ko].x = pk2(v0.x, v0.y); afr[ko].y = pk2(v0.z, v0.w);
                afr[ko].z = pk2(v1.x, v1.y); afr[ko].w = pk2(v1.z, v1.w);
              }
            }
            if (s8 == 3) {
#pragma unroll
              for (int ko = 2; ko < 4; ++ko) {
                float4 v0 = lv[2*ko], v1 = lv[2*ko+1];
                afr[ko].x = pk2(v0.x, v0.y); afr[ko].y = pk2(v0.z, v0.w);
                afr[ko].z = pk2(v1.x, v1.y); afr[ko].w = pk2(v1.z, v1.w);
              }
            }
          } else {
            const int nt = s8 >> 1;      // compile-time (s8 unrolled)
            if ((s8 & 1) == 0) {
              aacc = MF(afr[1], bfA[nt][1], MF(afr[0], bfA[nt][0], Z));
            } else {
              aacc = MF(afr[3], bfA[nt][3], MF(afr[2], bfA[nt][2], aacc));
              int n = wv * 64 + nt * 16 + r15;
              int t0 = tt*16 + kg*4;
              u32 off = (u32)(n*128 + ((t0*2) ^ ((n & 7) << 4)));
              uint2 pw; pw.x = pk2(aacc[0], aacc[1]); pw.y = pk2(aacc[2], aacc[3]);
              *(uint2*)(xgN + off) = pw;
            }
          }
        }

        // ---- recurrence step ----
        uint4 a0 = *(const uint4*)(lds + rdh +   0 + kg*16);
        uint4 a1 = *(const uint4*)(lds + rdh +  64 + kg*16);
        uint4 a2 = *(const uint4*)(lds + rdh + 128 + kg*16);
        uint4 a3 = *(const uint4*)(lds + rdh + 192 + kg*16);
        f32x4 aci = MF(a0, bw[0][0], Z);
        f32x4 acf = MF(a0, bw[1][0], Z);
        f32x4 acg = MF(a0, bw[2][0], Z);
        f32x4 aco = MF(a0, bw[3][0], Z);
        aci = MF(a1, bw[0][1], aci); acf = MF(a1, bw[1][1], acf);
        acg = MF(a1, bw[2][1], acg); aco = MF(a1, bw[3][1], aco);
        aci = MF(a2, bw[0][2], aci); acf = MF(a2, bw[1][2], acf);
        acg = MF(a2, bw[2][2], acg); aco = MF(a2, bw[3][2], aco);
        aci = MF(a3, bw[0][3], aci); acf = MF(a3, bw[1][3], acf);
        acg = MF(a3, bw[2][3], acg); aco = MF(a3, bw[3][3], aco);
        float gi = aci[0] + (float)xh[0][s8];
        float gf = acf[0] + (float)xh[1][s8];
        float gg = acg[0] + (float)xh[2][s8];
        float go = aco[0] + (float)xh[3][s8];
        float si = __builtin_amdgcn_rcpf(1.f + fexp2(gi));
        float sf = __builtin_amdgcn_rcpf(1.f + fexp2(gf));
        float sg = __builtin_fmaf(2.f, __builtin_amdgcn_rcpf(1.f + fexp2(gg)), -1.f);
        float so = __builtin_amdgcn_rcpf(1.f + fexp2(go));
        c = __builtin_fmaf(sf, c, si * sg);
        float th = __builtin_fmaf(2.f,
                     __builtin_amdgcn_rcpf(1.f + fexp2(c * -2.885390082f)), -1.f);
        float hval = so * th;
        if (l < 16) *(__fp16*)(lds + wrh + j * 2) = (__fp16)hval;
        u32 tswap = rdh; rdh = wrh; wrh = tswap;
        __syncthreads();
      }
    }
    cur ^= 1;
  }

  // ---- tail: out[b][n] = h_final @ w_out ----
  if (tid < DH) {
    int n = tid;
    const u32* hf = (const u32*)(lds + rdh);   // final h (f16 pairs)
    float acc = 0.f;
#pragma unroll 8
    for (int kk = 0; kk < 64; ++kk) {
      half2_t h2v = __builtin_bit_cast(half2_t, hf[kk]);
      acc = __builtin_fmaf((float)h2v[0], w_out[(2*kk)*DH + n],
            __builtin_fmaf((float)h2v[1], w_out[(2*kk+1)*DH + n], acc));
    }
    out[b * DH + n] = acc;
  }
}

extern "C" void kernel_launch(void* const* d_in, const int* in_sizes, int n_in,
                              void* d_out, int out_size, void* d_ws, size_t ws_size,
                              hipStream_t stream) {
  const float* x    = (const float*)d_in[0];
  const float* x2i  = (const float*)d_in[1];
  const float* x2f  = (const float*)d_in[2];
  const float* x2g  = (const float*)d_in[3];
  const float* x2o  = (const float*)d_in[4];
  const float* h2i  = (const float*)d_in[5];
  const float* h2f  = (const float*)d_in[6];
  const float* h2g  = (const float*)d_in[7];
  const float* h2o  = (const float*)d_in[8];
  const float* wout = (const float*)d_in[9];

  u32* wxT = (u32*)d_ws;            // 512*64*4 = 128 KB
  u32* whT = wxT + NC * 64;         // +128 KB

  (void)hipFuncSetAttribute((const void*)lstm_fused,
                            hipFuncAttributeMaxDynamicSharedMemorySize, LDS_TOTAL);

  pack_w<<<64, 512, 0, stream>>>(x2i, x2f, x2g, x2o, h2i, h2f, h2g, h2o, wxT, whT);
  lstm_fused<<<NBATCH, 512, LDS_TOTAL, stream>>>(x, wxT, whT, wout, (float*)d_out);
}

// Round 13
// 255.997 us; speedup vs baseline: 1.7839x; 1.0362x over previous
//
#include <hip/hip_runtime.h>

typedef unsigned int u32;
typedef __fp16 half2_t __attribute__((ext_vector_type(2)));
typedef __fp16 half8_t __attribute__((ext_vector_type(8)));
typedef float  f32x4   __attribute__((ext_vector_type(4)));
typedef int    i32x4   __attribute__((ext_vector_type(4)));

#define DIN 128
#define DH  128
#define SEQL 512
#define NBATCH 256
#define NC  512          // 4*DH fused gate columns
#define TC  64           // timesteps per chunk
#define NCHUNK (SEQL/TC) // 8

#define HOFF 131072              // i8 h dbuf after 2 xgT buffers (2 x 128 B)
#define HF2  (131072 + 256)      // final f16 h for tail (256 B)
#define LDS_TOTAL (131072 + 256 + 256)

__device__ __forceinline__ u32 pk2(float a, float b) {
  half2_t h = __builtin_amdgcn_cvt_pkrtz(a, b);
  return __builtin_bit_cast(u32, h);
}

__device__ __forceinline__ float fexp2(float x) {
#if defined(__has_builtin) && __has_builtin(__builtin_amdgcn_exp2f)
  return __builtin_amdgcn_exp2f(x);
#else
  return __builtin_exp2f(x);
#endif
}

#define MF(A, B, C) __builtin_amdgcn_mfma_f32_16x16x32_f16( \
    __builtin_bit_cast(half8_t, A), __builtin_bit_cast(half8_t, B), C, 0, 0, 0)
#define MFI8(A, B, C) __builtin_amdgcn_mfma_i32_16x16x64_i8( \
    __builtin_bit_cast(i32x4, A), __builtin_bit_cast(i32x4, B), C, 0, 0, 0)

// Pack fused x-projection weights into f16-pair column-major image,
// PRE-SCALED by the exp2 conversion constants (i,f,o: -log2e; g: -2log2e).
__global__ void pack_w(const float* __restrict__ x2i, const float* __restrict__ x2f,
                       const float* __restrict__ x2g, const float* __restrict__ x2o,
                       u32* __restrict__ wxT) {
  int idx = blockIdx.x * blockDim.x + threadIdx.x;   // 0..32767
  if (idx >= NC * 64) return;
  int j = idx >> 6, kk = idx & 63;
  int g = j >> 7, jjj = j & 127;
  const float* wx = (g == 0) ? x2i : (g == 1) ? x2f : (g == 2) ? x2g : x2o;
  float s = (g == 2) ? -2.885390082f : -1.442695041f;
  wxT[idx] = pk2(s * wx[(2*kk)*DH + jjj], s * wx[(2*kk+1)*DH + jjj]);
}

// Quantize recurrence weights to i8, per-column scale; dequant scale folds
// 1/(127*127) and the exp2 gate constant.
__global__ void pack_whi8(const float* __restrict__ h2i, const float* __restrict__ h2f,
                          const float* __restrict__ h2g, const float* __restrict__ h2o,
                          u32* __restrict__ whI, float* __restrict__ dqs) {
  int j = blockIdx.x * blockDim.x + threadIdx.x;   // 0..511 fused col
  if (j >= NC) return;
  int g = j >> 7, jj = j & 127;
  const float* wh = (g == 0) ? h2i : (g == 1) ? h2f : (g == 2) ? h2g : h2o;
  float amax = 1e-20f;
  for (int k = 0; k < DH; ++k) amax = fmaxf(amax, fabsf(wh[k*DH + jj]));
  float s = 127.f / amax;
  for (int kk = 0; kk < 32; ++kk) {
    u32 wword = 0;
#pragma unroll
    for (int t = 0; t < 4; ++t) {
      int q = (int)__builtin_rintf(wh[(4*kk + t)*DH + jj] * s);
      wword |= ((u32)(q & 0xFF)) << (8 * t);
    }
    whI[j*32 + kk] = wword;
  }
  dqs[j] = (amax / 16129.f) * ((g == 2) ? -2.885390082f : -1.442695041f);
}

// LDS: xgT[2] dbuf ([col][128 B of t] XOR-swizzled f16) + i8 h dbuf + f16 h.
// Recurrence gate-GEMM on mfma_i32_16x16x64_i8 (K=64 -> 8 MFMA/wave/step);
// c and nonlinearity stay f32 in-register. Phase A (f16) interleaved as r12.
__global__ __launch_bounds__(512, 2)
void lstm_fused(
    const float* __restrict__ x, const u32* __restrict__ wxT,
    const u32* __restrict__ whI, const float* __restrict__ dqs,
    const float* __restrict__ w_out, float* __restrict__ out) {
  extern __shared__ char lds[];

  const int tid = threadIdx.x;
  const int b   = blockIdx.x;
  const int l   = tid & 63, wv = tid >> 6;
  const int kg  = l >> 4, r15 = l & 15;
  const int j   = wv * 16 + r15;   // hidden index this lane owns

  // i8 recurrence B-frags: bi8[g][m] = whI[(g*128+j)*32][m*16+kg*4 ..+4]
  // (k = m*64 + kg*16 + [0,16))  -- 32 VGPRs
  uint4 bi8[4][2];
  float dqv[4];
#pragma unroll
  for (int g = 0; g < 4; ++g) {
    const uint4* wp = (const uint4*)(whI + (g * DH + j) * 32);
    bi8[g][0] = wp[kg];
    bi8[g][1] = wp[4 + kg];
    dqv[g] = dqs[g * DH + j];
  }
  // Phase-A B-frags (persistent, 64 VGPRs): this wave's 4 n-tiles
  uint4 bfA[4][4];
#pragma unroll
  for (int nt = 0; nt < 4; ++nt) {
    int n = wv * 64 + nt * 16 + r15;
#pragma unroll
    for (int ko = 0; ko < 4; ++ko)
      bfA[nt][ko] = *(const uint4*)(wxT + n*64 + ko*16 + kg*4);
  }

  if (tid < 64) ((u32*)(lds + HOFF))[tid] = 0u;   // zero both i8 h buffers
  float c = 0.f, lasth = 0.f;
  u32 rdh = HOFF;          // current h (i8[128])
  u32 wrh = HOFF + 128;    // next h
  const float* xb = x + (size_t)b * SEQL * DIN;
  const f32x4 Z  = {0.f, 0.f, 0.f, 0.f};
  const i32x4 ZI = {0, 0, 0, 0};
  __syncthreads();

  // ---- standalone phase A for chunk 0 -> buffer 0 ----
#pragma unroll 1
  for (int tt = 0; tt < 4; ++tt) {
    uint4 afr0[4];
#pragma unroll
    for (int ko = 0; ko < 4; ++ko) {
      const float4* xp = (const float4*)(xb + (size_t)(tt*16 + r15)*DIN + ko*32 + kg*8);
      float4 v0 = xp[0], v1 = xp[1];
      afr0[ko].x = pk2(v0.x, v0.y); afr0[ko].y = pk2(v0.z, v0.w);
      afr0[ko].z = pk2(v1.x, v1.y); afr0[ko].w = pk2(v1.z, v1.w);
    }
#pragma unroll
    for (int nt = 0; nt < 4; ++nt) {
      int n = wv * 64 + nt * 16 + r15;
      f32x4 acc = MF(afr0[0], bfA[nt][0], Z);
      acc = MF(afr0[1], bfA[nt][1], acc);
      acc = MF(afr0[2], bfA[nt][2], acc);
      acc = MF(afr0[3], bfA[nt][3], acc);
      int t0 = tt*16 + kg*4;
      u32 off = (u32)(n*128 + ((t0*2) ^ ((n & 7) << 4)));
      uint2 pw; pw.x = pk2(acc[0], acc[1]); pw.y = pk2(acc[2], acc[3]);
      *(uint2*)(lds + off) = pw;
    }
  }
  __syncthreads();

  int cur = 0;
#pragma unroll 1
  for (int ch = 0; ch < NCHUNK; ++ch) {
    char* xgC = lds + cur * 65536;
    char* xgN = lds + (cur ^ 1) * 65536;
    const bool doA = (ch + 1 < NCHUNK);
    float4 lv[8];    // staged x loads (even m)
    uint4  afr[4];   // f16 A-frags   (built even m, consumed odd m)
    f32x4  aacc;     // A accumulator (odd m, spans 2 steps)

#pragma unroll 1
    for (int m = 0; m < 8; ++m) {
      const int tt = m >> 1;
      // xg for col j of each gate, timesteps [8m, 8m+8)  (pre-scaled)
      half8_t xh[4];
#pragma unroll
      for (int g = 0; g < 4; ++g) {
        int cg = g * DH + j;
        xh[g] = __builtin_bit_cast(half8_t,
            *(const uint4*)(xgC + cg*128 + ((m*16) ^ ((cg & 7) << 4))));
      }
#pragma unroll
      for (int s8 = 0; s8 < 8; ++s8) {
        // ---- interleaved phase A (chunk ch+1) ----
        if (doA) {
          if ((m & 1) == 0) {
            if (s8 == 0) {
              const float* xr = xb + (size_t)((ch+1)*TC + tt*16 + r15)*DIN + kg*8;
#pragma unroll
              for (int ko = 0; ko < 4; ++ko) {
                const float4* xp = (const float4*)(xr + ko*32);
                lv[2*ko]   = xp[0];
                lv[2*ko+1] = xp[1];
              }
            }
            if (s8 == 2) {
#pragma unroll
              for (int ko = 0; ko < 2; ++ko) {
                float4 v0 = lv[2*ko], v1 = lv[2*ko+1];
                afr[ko].x = pk2(v0.x, v0.y); afr[ko].y = pk2(v0.z, v0.w);
                afr[ko].z = pk2(v1.x, v1.y); afr[ko].w = pk2(v1.z, v1.w);
              }
            }
            if (s8 == 3) {
#pragma unroll
              for (int ko = 2; ko < 4; ++ko) {
                float4 v0 = lv[2*ko], v1 = lv[2*ko+1];
                afr[ko].x = pk2(v0.x, v0.y); afr[ko].y = pk2(v0.z, v0.w);
                afr[ko].z = pk2(v1.x, v1.y); afr[ko].w = pk2(v1.z, v1.w);
              }
            }
          } else {
            const int nt = s8 >> 1;      // compile-time (s8 unrolled)
            if ((s8 & 1) == 0) {
              aacc = MF(afr[1], bfA[nt][1], MF(afr[0], bfA[nt][0], Z));
            } else {
              aacc = MF(afr[3], bfA[nt][3], MF(afr[2], bfA[nt][2], aacc));
              int n = wv * 64 + nt * 16 + r15;
              int t0 = tt*16 + kg*4;
              u32 off = (u32)(n*128 + ((t0*2) ^ ((n & 7) << 4)));
              uint2 pw; pw.x = pk2(aacc[0], aacc[1]); pw.y = pk2(aacc[2], aacc[3]);
              *(uint2*)(xgN + off) = pw;
            }
          }
        }

        // ---- recurrence step (i8 gate GEMM) ----
        uint4 a0 = *(const uint4*)(lds + rdh + kg*16);        // k = kg*16+[0,16)
        uint4 a1 = *(const uint4*)(lds + rdh + 64 + kg*16);   // k = 64+kg*16+[0,16)
        i32x4 aci = MFI8(a0, bi8[0][0], ZI);
        i32x4 acf = MFI8(a0, bi8[1][0], ZI);
        i32x4 acg = MFI8(a0, bi8[2][0], ZI);
        i32x4 aco = MFI8(a0, bi8[3][0], ZI);
        aci = MFI8(a1, bi8[0][1], aci);
        acf = MFI8(a1, bi8[1][1], acf);
        acg = MFI8(a1, bi8[2][1], acg);
        aco = MFI8(a1, bi8[3][1], aco);
        // dequant (scale folds 1/127^2 and -log2e / -2log2e) + pre-scaled xg
        float gi = __builtin_fmaf((float)aci[0], dqv[0], (float)xh[0][s8]);
        float gf = __builtin_fmaf((float)acf[0], dqv[1], (float)xh[1][s8]);
        float gg = __builtin_fmaf((float)acg[0], dqv[2], (float)xh[2][s8]);
        float go = __builtin_fmaf((float)aco[0], dqv[3], (float)xh[3][s8]);
        float si = __builtin_amdgcn_rcpf(1.f + fexp2(gi));
        float sf = __builtin_amdgcn_rcpf(1.f + fexp2(gf));
        float sg = __builtin_fmaf(2.f, __builtin_amdgcn_rcpf(1.f + fexp2(gg)), -1.f);
        float so = __builtin_amdgcn_rcpf(1.f + fexp2(go));
        c = __builtin_fmaf(sf, c, si * sg);
        float th = __builtin_fmaf(2.f,
                     __builtin_amdgcn_rcpf(1.f + fexp2(c * -2.885390082f)), -1.f);
        float hval = so * th;
        lasth = hval;
        int q = (int)__builtin_rintf(hval * 127.f);   // h in (-1,1): no clamp
        if (l < 16) *(char*)(lds + wrh + j) = (char)q;
        u32 tswap = rdh; rdh = wrh; wrh = tswap;
        __syncthreads();
      }
    }
    cur ^= 1;
  }

  // ---- publish exact final h as f16, then tail: out[b][n] = h @ w_out ----
  if (l < 16) *(__fp16*)(lds + HF2 + j * 2) = (__fp16)lasth;
  __syncthreads();
  if (tid < DH) {
    int n = tid;
    const u32* hf = (const u32*)(lds + HF2);   // final h (f16 pairs)
    float acc = 0.f;
#pragma unroll 8
    for (int kk = 0; kk < 64; ++kk) {
      half2_t h2v = __builtin_bit_cast(half2_t, hf[kk]);
      acc = __builtin_fmaf((float)h2v[0], w_out[(2*kk)*DH + n],
            __builtin_fmaf((float)h2v[1], w_out[(2*kk+1)*DH + n], acc));
    }
    out[b * DH + n] = acc;
  }
}

extern "C" void kernel_launch(void* const* d_in, const int* in_sizes, int n_in,
                              void* d_out, int out_size, void* d_ws, size_t ws_size,
                              hipStream_t stream) {
  const float* x    = (const float*)d_in[0];
  const float* x2i  = (const float*)d_in[1];
  const float* x2f  = (const float*)d_in[2];
  const float* x2g  = (const float*)d_in[3];
  const float* x2o  = (const float*)d_in[4];
  const float* h2i  = (const float*)d_in[5];
  const float* h2f  = (const float*)d_in[6];
  const float* h2g  = (const float*)d_in[7];
  const float* h2o  = (const float*)d_in[8];
  const float* wout = (const float*)d_in[9];

  u32*   wxT = (u32*)d_ws;                 // 32768 u32 = 128 KB
  u32*   whI = wxT + NC * 64;              // 16384 u32 =  64 KB
  float* dqs = (float*)(whI + NC * 32);    //   512 f32 =   2 KB

  (void)hipFuncSetAttribute((const void*)lstm_fused,
                            hipFuncAttributeMaxDynamicSharedMemorySize, LDS_TOTAL);

  pack_w<<<64, 512, 0, stream>>>(x2i, x2f, x2g, x2o, wxT);
  pack_whi8<<<1, 512, 0, stream>>>(h2i, h2f, h2g, h2o, whI, dqs);
  lstm_fused<<<NBATCH, 512, LDS_TOTAL, stream>>>(x, wxT, whI, dqs, wout, (float*)d_out);
}